// Round 2
// baseline (429.016 us; speedup 1.0000x reference)
//
#include <hip/hip_runtime.h>

typedef unsigned short u16;
typedef __bf16 bf16x8 __attribute__((ext_vector_type(8)));
typedef float f32x4 __attribute__((ext_vector_type(4)));

__device__ __forceinline__ u16 f2bf(float f) {
    unsigned int u = __builtin_bit_cast(unsigned int, f);
    u += 0x7fff + ((u >> 16) & 1);
    return (u16)(u >> 16);
}
__device__ __forceinline__ bf16x8 ldb8(const void* p) {
    return __builtin_bit_cast(bf16x8, *(const uint4*)p);
}
__device__ __forceinline__ f32x4 mfma16(bf16x8 a, bf16x8 b, f32x4 c) {
    return __builtin_amdgcn_mfma_f32_16x16x32_bf16(a, b, c, 0, 0, 0);
}

// ---------------------------------------------------------------------------
// Weight f32 -> bf16 (once per call, into ws)
// ---------------------------------------------------------------------------
__global__ __launch_bounds__(256) void cvt_w(const float* __restrict__ in,
                                             u16* __restrict__ out, int n4) {
    int i = blockIdx.x * 256 + threadIdx.x;
    const int stride = gridDim.x * 256;
    for (; i < n4; i += stride) {
        float4 v = ((const float4*)in)[i];
        unsigned p0 = (unsigned)f2bf(v.x) | ((unsigned)f2bf(v.y) << 16);
        unsigned p1 = (unsigned)f2bf(v.z) | ((unsigned)f2bf(v.w) << 16);
        ((uint2*)out)[i] = make_uint2(p0, p1);
    }
}

// ---------------------------------------------------------------------------
// GroupNorm stats: one block per (batch, group); group data contiguous. f32 in.
// ---------------------------------------------------------------------------
__global__ __launch_bounds__(256) void gn_stats(const float* __restrict__ in,
                                                float2* __restrict__ stats, int N) {
    const int tid = threadIdx.x;
    const long base = (long)blockIdx.x * N;
    float s = 0.f, s2 = 0.f;
    for (int i = tid * 4; i < N; i += 256 * 4) {
        float4 v = *(const float4*)(in + base + i);
        s += v.x + v.y + v.z + v.w;
        s2 += v.x * v.x + v.y * v.y + v.z * v.z + v.w * v.w;
    }
#pragma unroll
    for (int m = 1; m < 64; m <<= 1) { s += __shfl_xor(s, m); s2 += __shfl_xor(s2, m); }
    __shared__ float ps[4], ps2[4];
    const int w = tid >> 6;
    if ((tid & 63) == 0) { ps[w] = s; ps2[w] = s2; }
    __syncthreads();
    if (tid == 0) {
        float S = ps[0] + ps[1] + ps[2] + ps[3];
        float S2 = ps2[0] + ps2[1] + ps2[2] + ps2[3];
        float mu = S / (float)N;
        float var = S2 / (float)N - mu * mu;
        stats[blockIdx.x] = make_float2(mu, rsqrtf(var + 1e-5f));
    }
}

// ---------------------------------------------------------------------------
// GEMM with fused GroupNorm on activation (B, f32 in) + bias. W is bf16 (pre-cvt).
// out[b,o,n] = sum_c W[o,c]*gn(act[b,c,n]) + bias[o]
// Block tile 128x128, 4 waves (2x2), wave tile 64x64 = 4x4 MFMA frags.
// BF16OUT: write u16 (KV into ws) else f32 (Q into d_out).
// ---------------------------------------------------------------------------
template <bool BF16OUT>
__global__ __launch_bounds__(256) void gemm_gn(
    const u16* __restrict__ W, const float* __restrict__ act,
    const float2* __restrict__ stats, const float* __restrict__ gamma,
    const float* __restrict__ beta, const float* __restrict__ bias,
    void* __restrict__ outp, int K, int N, int CPG, long actBS, long outBS) {
    __shared__ u16 Blds[128][40];  // [n][k], pad 40 (80B stride, 16B aligned)
    const int tid = threadIdx.x;
    const int b = blockIdx.z;
    const int m0 = blockIdx.y * 128;
    const int n0 = blockIdx.x * 128;
    const int lane = tid & 63;
    const int w = tid >> 6;
    const int wr = w >> 1, wc = w & 1;
    const int l16 = lane & 15, g = lane >> 4;

    const float* actB = act + (long)b * actBS;
    f32x4 acc[4][4] = {};
    const int steps = K / 32;
    for (int s = 0; s < steps; ++s) {
        const int k0 = s * 32;
        __syncthreads();
#pragma unroll
        for (int r = 0; r < 4; ++r) {
            int idx = r * 256 + tid;        // 0..1023
            int kk = idx >> 5;              // 0..31
            int nn4 = (idx & 31) << 2;      // 0..124
            int kg = k0 + kk;
            float2 st = stats[b * 32 + kg / CPG];
            float gm = gamma[kg], bt = beta[kg];
            float4 v = *(const float4*)(actB + (long)kg * N + n0 + nn4);
            Blds[nn4 + 0][kk] = f2bf((v.x - st.x) * st.y * gm + bt);
            Blds[nn4 + 1][kk] = f2bf((v.y - st.x) * st.y * gm + bt);
            Blds[nn4 + 2][kk] = f2bf((v.z - st.x) * st.y * gm + bt);
            Blds[nn4 + 3][kk] = f2bf((v.w - st.x) * st.y * gm + bt);
        }
        __syncthreads();
        bf16x8 bfr[4];
#pragma unroll
        for (int ni = 0; ni < 4; ++ni)
            bfr[ni] = ldb8(&Blds[wc * 64 + ni * 16 + l16][g * 8]);
#pragma unroll
        for (int mi = 0; mi < 4; ++mi) {
            int row = m0 + wr * 64 + mi * 16 + l16;
            bf16x8 afr = ldb8(W + (long)row * K + k0 + g * 8);
#pragma unroll
            for (int ni = 0; ni < 4; ++ni)
                acc[mi][ni] = mfma16(afr, bfr[ni], acc[mi][ni]);
        }
    }
#pragma unroll
    for (int mi = 0; mi < 4; ++mi)
#pragma unroll
        for (int i = 0; i < 4; ++i) {
            int row = m0 + wr * 64 + mi * 16 + g * 4 + i;
            float bs = bias[row];
#pragma unroll
            for (int ni = 0; ni < 4; ++ni) {
                int col = n0 + wc * 64 + ni * 16 + l16;
                float v = acc[mi][ni][i] + bs;
                if (BF16OUT)
                    ((u16*)outp)[(long)b * outBS + (long)row * N + col] = f2bf(v);
                else
                    ((float*)outp)[(long)b * outBS + (long)row * N + col] = v;
            }
        }
}

// ---------------------------------------------------------------------------
// Attention: block per (b,h, 64-t tile); 4 waves x 16 t each.
// S'[s,t] = sum_d k[d,s] q[d,t] / 64 ; softmax over s ; O[d,t] = sum_s v[d,s] P[s,t]
// q (f32) read from d_out, output (f32) written in place over q (own tile only).
// kv is bf16 in ws.
// ---------------------------------------------------------------------------
__global__ __launch_bounds__(256) void attn_kernel(const float* q, const u16* __restrict__ kv,
                                                   float* out) {
    __shared__ u16 kT[128][72];        // [s-half][d]
    __shared__ u16 qT[64][72];         // [t][d]
    __shared__ u16 P[4][16][264];      // per-wave [t][s]
    const int tid = threadIdx.x;
    const int bh = blockIdx.y;
    const int b = bh >> 3, h = bh & 7;
    const int t0 = blockIdx.x * 64;
    const int lane = tid & 63, w = tid >> 6;
    const int l16 = lane & 15, g = lane >> 4;

    const long kbase = ((long)(b * 1024 + h * 64)) * 256;
    const long vbase = ((long)(b * 1024 + 512 + h * 64)) * 256;
    const long qbase = ((long)(b * 512 + h * 64)) * 4096 + t0;

    // stage qT[t][d] from f32 q
#pragma unroll
    for (int r = 0; r < 4; ++r) {
        int idx = r * 256 + tid;    // 0..1023
        int d = idx >> 4;           // 0..63
        int tt4 = (idx & 15) << 2;  // 0..60
        float4 v = *(const float4*)(q + qbase + (long)d * 4096 + tt4);
        qT[tt4 + 0][d] = f2bf(v.x);
        qT[tt4 + 1][d] = f2bf(v.y);
        qT[tt4 + 2][d] = f2bf(v.z);
        qT[tt4 + 3][d] = f2bf(v.w);
    }

    f32x4 sacc[16] = {};
#pragma unroll
    for (int half = 0; half < 2; ++half) {
        __syncthreads();  // qT staged (first iter) / previous kT reads done
#pragma unroll
        for (int r = 0; r < 4; ++r) {
            int idx = r * 256 + tid;    // 0..1023
            int d = idx >> 4;           // 0..63
            int ss = (idx & 15) << 3;   // 0..120
            union { uint4 v; u16 h8[8]; } u;
            u.v = *(const uint4*)(kv + kbase + (long)d * 256 + half * 128 + ss);
#pragma unroll
            for (int i = 0; i < 8; ++i) kT[ss + i][d] = u.h8[i];
        }
        __syncthreads();
#pragma unroll
        for (int kk = 0; kk < 2; ++kk) {
            int d0 = kk * 32 + g * 8;
            bf16x8 bq_ = ldb8(&qT[w * 16 + l16][d0]);
#pragma unroll
            for (int mi = 0; mi < 8; ++mi) {
                bf16x8 ak = ldb8(&kT[mi * 16 + l16][d0]);
                sacc[half * 8 + mi] = mfma16(ak, bq_, sacc[half * 8 + mi]);
            }
        }
    }

    // softmax over s for column t = t0 + w*16 + l16 (this thread holds 64 of 256 s)
    const float sc = 1.0f / 64.0f;
    float m = -3e38f;
#pragma unroll
    for (int f = 0; f < 16; ++f)
#pragma unroll
        for (int i = 0; i < 4; ++i) {
            float v = sacc[f][i] * sc;
            sacc[f][i] = v;
            m = fmaxf(m, v);
        }
    m = fmaxf(m, __shfl_xor(m, 16));
    m = fmaxf(m, __shfl_xor(m, 32));
    float sum = 0.f;
#pragma unroll
    for (int f = 0; f < 16; ++f)
#pragma unroll
        for (int i = 0; i < 4; ++i) {
            float p = __expf(sacc[f][i] - m);
            sacc[f][i] = p;
            sum += p;
        }
    sum += __shfl_xor(sum, 16);
    sum += __shfl_xor(sum, 32);
    const float inv = 1.0f / sum;

    // write P[t][s]; s = (f>>3)*128 + (f&7)*16 + g*4 + i
#pragma unroll
    for (int f = 0; f < 16; ++f) {
        u16 h4[4];
#pragma unroll
        for (int i = 0; i < 4; ++i) h4[i] = f2bf(sacc[f][i] * inv);
        uint2 pk;
        pk.x = (unsigned)h4[0] | ((unsigned)h4[1] << 16);
        pk.y = (unsigned)h4[2] | ((unsigned)h4[3] << 16);
        int s0 = (f >> 3) * 128 + (f & 7) * 16 + g * 4;
        *(uint2*)&P[w][l16][s0] = pk;
    }
    __syncthreads();  // order P u16 writes before uint4 reads

    // PV: O[d,t] += v[d,s] * P[s,t]
    f32x4 oacc[4] = {};
#pragma unroll
    for (int kk = 0; kk < 8; ++kk) {
        int s0 = kk * 32 + g * 8;
        bf16x8 bp = ldb8(&P[w][l16][s0]);
#pragma unroll
        for (int mi = 0; mi < 4; ++mi) {
            bf16x8 av = ldb8(kv + vbase + (long)(mi * 16 + l16) * 256 + s0);
            oacc[mi] = mfma16(av, bp, oacc[mi]);
        }
    }
#pragma unroll
    for (int mi = 0; mi < 4; ++mi)
#pragma unroll
        for (int i = 0; i < 4; ++i) {
            int d = mi * 16 + g * 4 + i;
            out[qbase + (long)d * 4096 + w * 16 + l16] = oacc[mi][i];
        }
}

// ---------------------------------------------------------------------------
// Final projection + residual, in place over d_out (attn tile staged to LDS first).
// y[b,o,l] = x[b,o,l] + sum_c wo[o,c]*attn[b,c,l] + bo[o]
// Block: all 512 rows x 32 cols. wo is bf16 (pre-cvt).
// ---------------------------------------------------------------------------
__global__ __launch_bounds__(256) void out_gemm(const u16* __restrict__ wo, const float* attn,
                                                const float* __restrict__ bo,
                                                const float* __restrict__ x, float* out) {
    __shared__ u16 A2[32][520];  // [l][c]
    const int tid = threadIdx.x;
    const int b = blockIdx.z;
    const int l0 = blockIdx.x * 32;
    const int lane = tid & 63, w = tid >> 6;
    const int l16 = lane & 15, g = lane >> 4;
    const long base = (long)b * 512 * 4096 + l0;

#pragma unroll
    for (int r = 0; r < 16; ++r) {
        int idx = r * 256 + tid;    // 0..4095
        int c = idx >> 3;           // 0..511
        int nn4 = (idx & 7) << 2;   // 0..28
        float4 v = *(const float4*)(attn + base + (long)c * 4096 + nn4);
        A2[nn4 + 0][c] = f2bf(v.x);
        A2[nn4 + 1][c] = f2bf(v.y);
        A2[nn4 + 2][c] = f2bf(v.z);
        A2[nn4 + 3][c] = f2bf(v.w);
    }
    __syncthreads();

    f32x4 acc[8][2] = {};
    for (int ks = 0; ks < 16; ++ks) {
        int k0 = ks * 32;
        bf16x8 b0 = ldb8(&A2[l16][k0 + g * 8]);
        bf16x8 b1 = ldb8(&A2[16 + l16][k0 + g * 8]);
#pragma unroll
        for (int mi = 0; mi < 8; ++mi) {
            int row = w * 128 + mi * 16 + l16;
            bf16x8 afr = ldb8(wo + (long)row * 512 + k0 + g * 8);
            acc[mi][0] = mfma16(afr, b0, acc[mi][0]);
            acc[mi][1] = mfma16(afr, b1, acc[mi][1]);
        }
    }
#pragma unroll
    for (int mi = 0; mi < 8; ++mi)
#pragma unroll
        for (int i = 0; i < 4; ++i) {
            int row = w * 128 + mi * 16 + g * 4 + i;
            float bs = bo[row];
#pragma unroll
            for (int ni = 0; ni < 2; ++ni) {
                long off = (long)b * 512 * 4096 + (long)row * 4096 + l0 + ni * 16 + l16;
                out[off] = acc[mi][ni][i] + bs + x[off];
            }
        }
}

// ---------------------------------------------------------------------------
extern "C" void kernel_launch(void* const* d_in, const int* in_sizes, int n_in,
                              void* d_out, int out_size, void* d_ws, size_t ws_size,
                              hipStream_t stream) {
    const float* x     = (const float*)d_in[0];
    const float* ctx   = (const float*)d_in[1];
    const float* gnx_g = (const float*)d_in[2];
    const float* gnx_b = (const float*)d_in[3];
    const float* gnc_g = (const float*)d_in[4];
    const float* gnc_b = (const float*)d_in[5];
    const float* wq    = (const float*)d_in[6];
    const float* bq    = (const float*)d_in[7];
    const float* wkv   = (const float*)d_in[8];
    const float* bkv   = (const float*)d_in[9];
    const float* wo    = (const float*)d_in[10];
    const float* bo    = (const float*)d_in[11];
    float* out = (float*)d_out;

    char* ws = (char*)d_ws;
    float2* stats_x = (float2*)ws;                    // 2048 B
    float2* stats_c = (float2*)(ws + 2048);           // 2048 B
    u16* wq_bf  = (u16*)(ws + 4096);                  // 512*512   = 524288 B
    u16* wkv_bf = (u16*)(ws + 528384);                // 1024*768  = 1572864 B
    u16* wo_bf  = (u16*)(ws + 2101248);               // 512*512   = 524288 B
    u16* kv     = (u16*)(ws + 2625536);               // 8*1024*256*2 = 4 MB

    // 0) weights -> bf16
    cvt_w<<<dim3(256), dim3(256), 0, stream>>>(wq, wq_bf, 512 * 512 / 4);
    cvt_w<<<dim3(256), dim3(256), 0, stream>>>(wkv, wkv_bf, 1024 * 768 / 4);
    cvt_w<<<dim3(256), dim3(256), 0, stream>>>(wo, wo_bf, 512 * 512 / 4);

    // 1) GroupNorm stats (8 batches x 32 groups = 256 blocks each)
    gn_stats<<<dim3(256), dim3(256), 0, stream>>>(x, stats_x, 16 * 4096);
    gn_stats<<<dim3(256), dim3(256), 0, stream>>>(ctx, stats_c, 24 * 256);

    // 2) Q = wq @ gn(x) + bq -> d_out (f32)   M=512 K=512 N=4096
    gemm_gn<false><<<dim3(32, 4, 8), dim3(256), 0, stream>>>(
        wq_bf, x, stats_x, gnx_g, gnx_b, bq, out, 512, 4096, 16,
        (long)512 * 4096, (long)512 * 4096);

    // 3) KV = wkv @ gn(ctx) + bkv -> ws (bf16)  M=1024 K=768 N=256
    gemm_gn<true><<<dim3(2, 8, 8), dim3(256), 0, stream>>>(
        wkv_bf, ctx, stats_c, gnc_g, gnc_b, bkv, kv, 768, 256, 24,
        (long)768 * 256, (long)1024 * 256);

    // 4) attention, in place over q in d_out
    attn_kernel<<<dim3(64, 64), dim3(256), 0, stream>>>(out, kv, out);

    // 5) y = x + wo @ attn + bo, in place over d_out
    out_gemm<<<dim3(128, 1, 8), dim3(256), 0, stream>>>(wo_bf, out, bo, x, out);
}

// Round 3
// 305.198 us; speedup vs baseline: 1.4057x; 1.4057x over previous
//
#include <hip/hip_runtime.h>

typedef unsigned short u16;
typedef __bf16 bf16x8 __attribute__((ext_vector_type(8)));
typedef float f32x4 __attribute__((ext_vector_type(4)));

__device__ __forceinline__ u16 f2bf(float f) {
    unsigned int u = __builtin_bit_cast(unsigned int, f);
    u += 0x7fff + ((u >> 16) & 1);
    return (u16)(u >> 16);
}
__device__ __forceinline__ bf16x8 ldb8(const void* p) {
    return __builtin_bit_cast(bf16x8, *(const uint4*)p);
}
__device__ __forceinline__ f32x4 mfma16(bf16x8 a, bf16x8 b, f32x4 c) {
    return __builtin_amdgcn_mfma_f32_16x16x32_bf16(a, b, c, 0, 0, 0);
}

// ---------------------------------------------------------------------------
// Weight f32 -> bf16 (once per call, into ws)
// ---------------------------------------------------------------------------
__global__ __launch_bounds__(256) void cvt_w(const float* __restrict__ in,
                                             u16* __restrict__ out, int n4) {
    int i = blockIdx.x * 256 + threadIdx.x;
    const int stride = gridDim.x * 256;
    for (; i < n4; i += stride) {
        float4 v = ((const float4*)in)[i];
        unsigned p0 = (unsigned)f2bf(v.x) | ((unsigned)f2bf(v.y) << 16);
        unsigned p1 = (unsigned)f2bf(v.z) | ((unsigned)f2bf(v.w) << 16);
        ((uint2*)out)[i] = make_uint2(p0, p1);
    }
}

// ---------------------------------------------------------------------------
// GroupNorm stats: one block per (batch, group); group data contiguous. f32 in.
// ---------------------------------------------------------------------------
__global__ __launch_bounds__(256) void gn_stats(const float* __restrict__ in,
                                                float2* __restrict__ stats, int N) {
    const int tid = threadIdx.x;
    const long base = (long)blockIdx.x * N;
    float s = 0.f, s2 = 0.f;
    for (int i = tid * 4; i < N; i += 256 * 4) {
        float4 v = *(const float4*)(in + base + i);
        s += v.x + v.y + v.z + v.w;
        s2 += v.x * v.x + v.y * v.y + v.z * v.z + v.w * v.w;
    }
#pragma unroll
    for (int m = 1; m < 64; m <<= 1) { s += __shfl_xor(s, m); s2 += __shfl_xor(s2, m); }
    __shared__ float ps[4], ps2[4];
    const int w = tid >> 6;
    if ((tid & 63) == 0) { ps[w] = s; ps2[w] = s2; }
    __syncthreads();
    if (tid == 0) {
        float S = ps[0] + ps[1] + ps[2] + ps[3];
        float S2 = ps2[0] + ps2[1] + ps2[2] + ps2[3];
        float mu = S / (float)N;
        float var = S2 / (float)N - mu * mu;
        stats[blockIdx.x] = make_float2(mu, rsqrtf(var + 1e-5f));
    }
}

// ---------------------------------------------------------------------------
// big_gemm: out[b,o,n] = sum_c W[o,c]*xform(B[b,c,n]) + bias[o] (+X resid)
// M=512 (full), K=512, N-tile=64. 4 waves, wave tile 128M x 64N.
// B fetched exactly once from HBM. W (bf16) re-read from L2 per block.
// GN: apply GroupNorm to B rows. RESID: add X at epilogue.
// ---------------------------------------------------------------------------
template <bool GN, bool RESID>
__global__ __launch_bounds__(256, 2) void big_gemm(
    const u16* __restrict__ W, const float* __restrict__ B,
    const float2* __restrict__ stats, const float* __restrict__ gamma,
    const float* __restrict__ beta, const float* __restrict__ bias,
    const float* __restrict__ X, float* __restrict__ out) {
    constexpr int K = 512, N = 4096, CPG = 16;
    __shared__ u16 Blds[64][64];  // [n][k], stride 128B, XOR-swizzled k
    const int tid = threadIdx.x;
    const int b = blockIdx.z;
    const int n0 = blockIdx.x * 64;
    const int lane = tid & 63, w = tid >> 6;
    const int l16 = lane & 15, g = lane >> 4;
    const float* Bb = B + (long)b * K * N;

    f32x4 acc[8][4] = {};
    for (int c = 0; c < 8; ++c) {
        const int k0 = c * 64;
        __syncthreads();
#pragma unroll
        for (int r = 0; r < 4; ++r) {
            int idx = r * 256 + tid;     // 0..1023
            int kk = idx >> 4;           // 0..63
            int n4 = (idx & 15) << 2;    // 0..60
            int kg = k0 + kk;
            float4 v = *(const float4*)(Bb + (long)kg * N + n0 + n4);
            if (GN) {
                float2 st = stats[b * 32 + kg / CPG];
                float gm = gamma[kg], bt = beta[kg];
                v.x = (v.x - st.x) * st.y * gm + bt;
                v.y = (v.y - st.x) * st.y * gm + bt;
                v.z = (v.z - st.x) * st.y * gm + bt;
                v.w = (v.w - st.x) * st.y * gm + bt;
            }
            float vv[4] = {v.x, v.y, v.z, v.w};
#pragma unroll
            for (int jj = 0; jj < 4; ++jj) {
                int j = (jj + (lane & 3)) & 3;   // rotate to spread store banks
                int row = n4 + j;
                Blds[row][kk ^ ((row & 7) << 3)] = f2bf(vv[j]);
            }
        }
        __syncthreads();
#pragma unroll
        for (int kk = 0; kk < 2; ++kk) {
            bf16x8 bfr[4];
#pragma unroll
            for (int ni = 0; ni < 4; ++ni) {
                int row = ni * 16 + l16;
                bfr[ni] = ldb8(&Blds[row][(kk * 32 + g * 8) ^ ((row & 7) << 3)]);
            }
#pragma unroll
            for (int mi = 0; mi < 8; ++mi) {
                int arow = w * 128 + mi * 16 + l16;
                bf16x8 afr = ldb8(W + (long)arow * K + k0 + kk * 32 + g * 8);
#pragma unroll
                for (int ni = 0; ni < 4; ++ni)
                    acc[mi][ni] = mfma16(afr, bfr[ni], acc[mi][ni]);
            }
        }
    }
    const long ob = (long)b * K * N;
#pragma unroll
    for (int mi = 0; mi < 8; ++mi)
#pragma unroll
        for (int i = 0; i < 4; ++i) {
            int row = w * 128 + mi * 16 + g * 4 + i;
            float bs = bias[row];
#pragma unroll
            for (int ni = 0; ni < 4; ++ni) {
                int col = n0 + ni * 16 + l16;
                long off = ob + (long)row * N + col;
                float v = acc[mi][ni][i] + bs;
                if (RESID) v += X[off];
                out[off] = v;
            }
        }
}

// ---------------------------------------------------------------------------
// KV GEMM with fused GroupNorm (small: M=1024,K=768,N=256). Tile 128x128.
// ---------------------------------------------------------------------------
__global__ __launch_bounds__(256) void gemm_kv(
    const u16* __restrict__ W, const float* __restrict__ act,
    const float2* __restrict__ stats, const float* __restrict__ gamma,
    const float* __restrict__ beta, const float* __restrict__ bias,
    u16* __restrict__ outp, int K, int N, int CPG, long actBS, long outBS) {
    __shared__ u16 Blds[128][40];
    const int tid = threadIdx.x;
    const int b = blockIdx.z;
    const int m0 = blockIdx.y * 128;
    const int n0 = blockIdx.x * 128;
    const int lane = tid & 63;
    const int w = tid >> 6;
    const int wr = w >> 1, wc = w & 1;
    const int l16 = lane & 15, g = lane >> 4;

    const float* actB = act + (long)b * actBS;
    f32x4 acc[4][4] = {};
    const int steps = K / 32;
    for (int s = 0; s < steps; ++s) {
        const int k0 = s * 32;
        __syncthreads();
#pragma unroll
        for (int r = 0; r < 4; ++r) {
            int idx = r * 256 + tid;
            int kk = idx >> 5;
            int n4 = (idx & 31) << 2;
            int kg = k0 + kk;
            float2 st = stats[b * 32 + kg / CPG];
            float gm = gamma[kg], bt = beta[kg];
            float4 v = *(const float4*)(actB + (long)kg * N + n0 + n4);
            Blds[n4 + 0][kk] = f2bf((v.x - st.x) * st.y * gm + bt);
            Blds[n4 + 1][kk] = f2bf((v.y - st.x) * st.y * gm + bt);
            Blds[n4 + 2][kk] = f2bf((v.z - st.x) * st.y * gm + bt);
            Blds[n4 + 3][kk] = f2bf((v.w - st.x) * st.y * gm + bt);
        }
        __syncthreads();
        bf16x8 bfr[4];
#pragma unroll
        for (int ni = 0; ni < 4; ++ni)
            bfr[ni] = ldb8(&Blds[wc * 64 + ni * 16 + l16][g * 8]);
#pragma unroll
        for (int mi = 0; mi < 4; ++mi) {
            int row = m0 + wr * 64 + mi * 16 + l16;
            bf16x8 afr = ldb8(W + (long)row * K + k0 + g * 8);
#pragma unroll
            for (int ni = 0; ni < 4; ++ni)
                acc[mi][ni] = mfma16(afr, bfr[ni], acc[mi][ni]);
        }
    }
#pragma unroll
    for (int mi = 0; mi < 4; ++mi)
#pragma unroll
        for (int i = 0; i < 4; ++i) {
            int row = m0 + wr * 64 + mi * 16 + g * 4 + i;
            float bs = bias[row];
#pragma unroll
            for (int ni = 0; ni < 4; ++ni) {
                int col = n0 + wc * 64 + ni * 16 + l16;
                outp[(long)b * outBS + (long)row * N + col] = f2bf(acc[mi][ni][i] + bs);
            }
        }
}

// ---------------------------------------------------------------------------
// Attention v2: block per (b,h, 64-t tile); 4 waves x 16 t.
// XOR-swizzled LDS (T2), P overlaid on kT/qT via union (LDS 32KB -> 5 blk/CU).
// ---------------------------------------------------------------------------
__global__ __launch_bounds__(256) void attn_kernel(const float* q, const u16* __restrict__ kv,
                                                   float* out) {
    __shared__ union {
        struct { u16 kT[128][64]; u16 qT[64][64]; } s;  // 24KB
        u16 P[4][16][256];                              // 32KB
    } sh;
    const int tid = threadIdx.x;
    const int bh = blockIdx.y;
    const int b = bh >> 3, h = bh & 7;
    const int t0 = blockIdx.x * 64;
    const int lane = tid & 63, w = tid >> 6;
    const int l16 = lane & 15, g = lane >> 4;

    const long kbase = ((long)(b * 1024 + h * 64)) * 256;
    const long vbase = ((long)(b * 1024 + 512 + h * 64)) * 256;
    const long qbase = ((long)(b * 512 + h * 64)) * 4096 + t0;

    // stage qT[t][d], swizzled col = d ^ ((t&7)<<3)
#pragma unroll
    for (int r = 0; r < 4; ++r) {
        int idx = r * 256 + tid;    // 0..1023
        int d = idx >> 4;           // 0..63
        int tt4 = (idx & 15) << 2;  // 0..60
        float4 v = *(const float4*)(q + qbase + (long)d * 4096 + tt4);
        float vv[4] = {v.x, v.y, v.z, v.w};
#pragma unroll
        for (int jj = 0; jj < 4; ++jj) {
            int j = (jj + (lane & 3)) & 3;
            int row = tt4 + j;
            sh.s.qT[row][d ^ ((row & 7) << 3)] = f2bf(vv[j]);
        }
    }

    f32x4 sacc[16] = {};
#pragma unroll
    for (int half = 0; half < 2; ++half) {
        __syncthreads();  // qT staged (first) / prior kT reads done
#pragma unroll
        for (int r = 0; r < 4; ++r) {
            int idx = r * 256 + tid;    // 0..1023
            int d = idx >> 4;           // 0..63
            int ss = (idx & 15) << 3;   // 0..120
            union { uint4 v; u16 h8[8]; } u;
            u.v = *(const uint4*)(kv + kbase + (long)d * 256 + half * 128 + ss);
#pragma unroll
            for (int jj = 0; jj < 8; ++jj) {
                int j = (jj + (lane & 7)) & 7;
                int row = ss + j;
                sh.s.kT[row][d ^ ((row & 7) << 3)] = u.h8[j];
            }
        }
        __syncthreads();
#pragma unroll
        for (int kk = 0; kk < 2; ++kk) {
            int d0 = kk * 32 + g * 8;
            int qrow = w * 16 + l16;
            bf16x8 bq_ = ldb8(&sh.s.qT[qrow][d0 ^ ((qrow & 7) << 3)]);
#pragma unroll
            for (int mi = 0; mi < 8; ++mi) {
                int krow = mi * 16 + l16;
                bf16x8 ak = ldb8(&sh.s.kT[krow][d0 ^ ((krow & 7) << 3)]);
                sacc[half * 8 + mi] = mfma16(ak, bq_, sacc[half * 8 + mi]);
            }
        }
    }
    __syncthreads();  // all QK^T LDS reads done before P overlays kT/qT

    // softmax over s for column t = t0 + w*16 + l16
    const float sc = 1.0f / 64.0f;
    float m = -3e38f;
#pragma unroll
    for (int f = 0; f < 16; ++f)
#pragma unroll
        for (int i = 0; i < 4; ++i) {
            float v = sacc[f][i] * sc;
            sacc[f][i] = v;
            m = fmaxf(m, v);
        }
    m = fmaxf(m, __shfl_xor(m, 16));
    m = fmaxf(m, __shfl_xor(m, 32));
    float sum = 0.f;
#pragma unroll
    for (int f = 0; f < 16; ++f)
#pragma unroll
        for (int i = 0; i < 4; ++i) {
            float p = __expf(sacc[f][i] - m);
            sacc[f][i] = p;
            sum += p;
        }
    sum += __shfl_xor(sum, 16);
    sum += __shfl_xor(sum, 32);
    const float inv = 1.0f / sum;

    // write P[t][s] swizzled; s = (f>>3)*128 + (f&7)*16 + g*4 + i
#pragma unroll
    for (int f = 0; f < 16; ++f) {
        u16 h4[4];
#pragma unroll
        for (int i = 0; i < 4; ++i) h4[i] = f2bf(sacc[f][i] * inv);
        uint2 pk;
        pk.x = (unsigned)h4[0] | ((unsigned)h4[1] << 16);
        pk.y = (unsigned)h4[2] | ((unsigned)h4[3] << 16);
        int s0 = (f >> 3) * 128 + (f & 7) * 16 + g * 4;
        int col = s0 ^ ((l16 & 7) << 3);
        *(uint2*)&sh.P[w][l16][col] = pk;
    }
    __syncthreads();

    // PV: O[d,t] += v[d,s] * P[s,t]; V from global (L2-resident)
    f32x4 oacc[4] = {};
#pragma unroll
    for (int kk = 0; kk < 8; ++kk) {
        int s0 = kk * 32 + g * 8;
        bf16x8 bp = ldb8(&sh.P[w][l16][s0 ^ ((l16 & 7) << 3)]);
#pragma unroll
        for (int mi = 0; mi < 4; ++mi) {
            bf16x8 av = ldb8(kv + vbase + (long)(mi * 16 + l16) * 256 + s0);
            oacc[mi] = mfma16(av, bp, oacc[mi]);
        }
    }
#pragma unroll
    for (int mi = 0; mi < 4; ++mi)
#pragma unroll
        for (int i = 0; i < 4; ++i) {
            int d = mi * 16 + g * 4 + i;
            out[qbase + (long)d * 4096 + w * 16 + l16] = oacc[mi][i];
        }
}

// ---------------------------------------------------------------------------
extern "C" void kernel_launch(void* const* d_in, const int* in_sizes, int n_in,
                              void* d_out, int out_size, void* d_ws, size_t ws_size,
                              hipStream_t stream) {
    const float* x     = (const float*)d_in[0];
    const float* ctx   = (const float*)d_in[1];
    const float* gnx_g = (const float*)d_in[2];
    const float* gnx_b = (const float*)d_in[3];
    const float* gnc_g = (const float*)d_in[4];
    const float* gnc_b = (const float*)d_in[5];
    const float* wq    = (const float*)d_in[6];
    const float* bq    = (const float*)d_in[7];
    const float* wkv   = (const float*)d_in[8];
    const float* bkv   = (const float*)d_in[9];
    const float* wo    = (const float*)d_in[10];
    const float* bo    = (const float*)d_in[11];
    float* out = (float*)d_out;

    char* ws = (char*)d_ws;
    float2* stats_x = (float2*)ws;                    // 2048 B
    float2* stats_c = (float2*)(ws + 2048);           // 2048 B
    u16* wq_bf  = (u16*)(ws + 4096);                  // 512KB
    u16* wkv_bf = (u16*)(ws + 528384);                // 1.5MB
    u16* wo_bf  = (u16*)(ws + 2101248);               // 512KB
    u16* kv     = (u16*)(ws + 2625536);               // 4MB

    cvt_w<<<dim3(256), dim3(256), 0, stream>>>(wq, wq_bf, 512 * 512 / 4);
    cvt_w<<<dim3(256), dim3(256), 0, stream>>>(wkv, wkv_bf, 1024 * 768 / 4);
    cvt_w<<<dim3(256), dim3(256), 0, stream>>>(wo, wo_bf, 512 * 512 / 4);

    gn_stats<<<dim3(256), dim3(256), 0, stream>>>(x, stats_x, 16 * 4096);
    gn_stats<<<dim3(256), dim3(256), 0, stream>>>(ctx, stats_c, 24 * 256);

    // Q = wq @ gn(x) + bq -> d_out (f32)
    big_gemm<true, false><<<dim3(64, 1, 8), dim3(256), 0, stream>>>(
        wq_bf, x, stats_x, gnx_g, gnx_b, bq, nullptr, out);

    // KV = wkv @ gn(ctx) + bkv -> ws (bf16)
    gemm_kv<<<dim3(2, 8, 8), dim3(256), 0, stream>>>(
        wkv_bf, ctx, stats_c, gnc_g, gnc_b, bkv, kv, 768, 256, 24,
        (long)768 * 256, (long)1024 * 256);

    // attention, in place over q in d_out
    attn_kernel<<<dim3(64, 64), dim3(256), 0, stream>>>(out, kv, out);

    // y = x + wo @ attn + bo, in place over d_out
    big_gemm<false, true><<<dim3(64, 1, 8), dim3(256), 0, stream>>>(
        wo_bf, out, nullptr, nullptr, nullptr, bo, x, out);
}